// Round 7
// baseline (279.564 us; speedup 1.0000x reference)
//
#include <hip/hip_runtime.h>

typedef __bf16 bf16;
typedef __bf16 bf16x8 __attribute__((ext_vector_type(8)));
typedef __bf16 bf16x4 __attribute__((ext_vector_type(4)));
typedef float  f32x4  __attribute__((ext_vector_type(4)));
typedef float  f32x16 __attribute__((ext_vector_type(16)));
typedef unsigned int u32;
typedef unsigned int u32x2 __attribute__((ext_vector_type(2)));
typedef unsigned int u32x4 __attribute__((ext_vector_type(4)));
typedef unsigned short u16;

#define MFMA16(a, b, c) __builtin_amdgcn_mfma_f32_16x16x32_bf16((a), (b), (c), 0, 0, 0)
#define MFMA32(a, b, c) __builtin_amdgcn_mfma_f32_32x32x16_bf16((a), (b), (c), 0, 0, 0)
#define L2E 1.4426950408889634f

// B=1, S=128, R=256, C=256, H=8, Ca=32.  M = S*R = 32768, K = 256.

// pack two f32 -> one u32 of 2 bf16 (lo, hi); compiler emits v_cvt_pk_bf16_f32
__device__ __forceinline__ u32 pk2(float lo, float hi) {
    u16 a = __builtin_bit_cast(u16, (bf16)lo);
    u16 b = __builtin_bit_cast(u16, (bf16)hi);
    return ((u32)b << 16) | (u32)a;
}

__device__ __forceinline__ bf16x8 cvt8(float4 a, float4 b) {
    bf16x8 t;
    t[0]=(bf16)a.x; t[1]=(bf16)a.y; t[2]=(bf16)a.z; t[3]=(bf16)a.w;
    t[4]=(bf16)b.x; t[5]=(bf16)b.y; t[6]=(bf16)b.z; t[7]=(bf16)b.w;
    return t;
}

// 2^x via v_exp_f32 (log2e pre-folded into scales at prep)
__device__ __forceinline__ float fexp2(float x) {
#if __has_builtin(__builtin_amdgcn_exp2f)
    return __builtin_amdgcn_exp2f(x);
#else
    return exp2f(x);
#endif
}
__device__ __forceinline__ float frcp(float x) {
#if __has_builtin(__builtin_amdgcn_rcpf)
    return __builtin_amdgcn_rcpf(x);
#else
    return 1.0f / x;
#endif
}

// ================= prep: bias transpose + weight transposes only ==============
__global__ __launch_bounds__(256) void prep_kernel(
    const float* __restrict__ bias,
    const float* __restrict__ w_q, const float* __restrict__ w_k,
    const float* __restrict__ w_v, const float* __restrict__ w_g,
    const float* __restrict__ w_o, const float* __restrict__ b_g,
    float* __restrict__ biasT,
    bf16* __restrict__ Wqg, bf16* __restrict__ Wkv, bf16* __restrict__ Wo,
    float* __restrict__ b_gL)
{
    // 1/sqrt(32) * log2(e): softmax computed in base-2 (exp2)
    const float norm = 0.17677669529663687f * L2E;
    const int gid = blockIdx.x * 256 + threadIdx.x;
    const int gsz = gridDim.x * 256;

    // biasT[h][q][k] <- bias[q][k][h] * log2e  (coalesced writes)
    for (int u = gid; u < 524288; u += gsz) {
        int h = u >> 16, qq = (u >> 8) & 255, kk = u & 255;
        biasT[u] = bias[(((qq << 8) + kk) << 3) + h] * L2E;
    }
    // Wqg[n][k]: n<256 -> w_q[k][n]*norm ; else w_g[k][n-256]*log2e (gate in base-2)
    for (int u = gid; u < 131072; u += gsz) {
        int n = u >> 8, k = u & 255;
        float v = (n < 256) ? w_q[k * 256 + n] * norm : w_g[k * 256 + (n - 256)] * L2E;
        Wqg[u] = (bf16)v;
    }
    // Wkv[n][k]: n<256 -> w_k[k][n] ; else w_v[k][n-256]
    for (int u = gid; u < 131072; u += gsz) {
        int n = u >> 8, k = u & 255;
        float v = (n < 256) ? w_k[k * 256 + n] : w_v[k * 256 + (n - 256)];
        Wkv[u] = (bf16)v;
    }
    // Wo[n][k] = w_o[k][n]   ([H*Ca][C] -> [C][H*Ca])
    for (int u = gid; u < 65536; u += gsz) {
        int n = u >> 8, k = u & 255;
        Wo[u] = (bf16)w_o[k * 256 + n];
    }
    // b_gL = b_g * log2e
    for (int u = gid; u < 256; u += gsz) b_gL[u] = b_g[u] * L2E;
}

// ============== streaming GEMM: C[M][ntot] = A[M][256] @ Bw[ntot][256]^T =======
// NO LDS, NO BARRIERS.  Rounds 4-6 lesson: with gll16 staging, every
// __syncthreads drains the whole vmcnt queue (incl. the prefetch), and 16 MFMAs
// (~80cy) can't cover ~500-900cy HBM latency at BK=32 -> the 2-phase pipeline
// never took (proj stuck ~55us, 2.5x its 22us HBM floor).  B (the weight) is
// L2-resident (<=0.26 MB), and its MFMA B-fragment [k=(l>>5)*8+j][n=l&31] is
// ONE bf16x8 load from the [n][k]-transposed weight; the A-fragment
// [m=l&31][k=(l>>5)*8+j] is 2 float4 + cvt (AMODE 1) or one bf16x8 (AMODE 0).
// 32x32x16 MFMA: 2x FLOP per operand-byte vs 16x16x32.  Scheduler hoists loads
// freely (no sync points); TLP (no LDS -> 3-4 waves/SIMD) hides the rest.
// Block = 128x128 (4 waves, each 64x64 = 2x2 32x32 frags), K=256 = 16 steps.
template<int AMODE, bool F32OUT>
__device__ __forceinline__ void sgemm_core(
    const void* __restrict__ Ap, const bf16* __restrict__ Bw,
    bf16* __restrict__ Cb, float* __restrict__ Cf, const float* __restrict__ bo,
    int m0, int n0, int ntot)
{
    const float* A32 = (const float*)Ap;
    const bf16*  A16 = (const bf16*)Ap;

    const int lane = threadIdx.x & 63, wave = threadIdx.x >> 6;
    const int l31 = lane & 31, hi = lane >> 5;        // hi in {0,1}: k-chunk
    const int wr = wave >> 1, wc = wave & 1;
    const int mbase = m0 + wr * 64;
    const int nbase = n0 + wc * 64;

    // element offsets (A rows stride 256; both A and Bw are [row][256])
    const size_t a0off = (size_t)(mbase + l31) * 256 + hi * 8;
    const size_t a1off = a0off + 32 * 256;
    const bf16* b0p = Bw + (size_t)(nbase + l31) * 256 + hi * 8;
    const bf16* b1p = b0p + 32 * 256;

    f32x16 acc00, acc01, acc10, acc11;
    #pragma unroll
    for (int i = 0; i < 16; ++i) { acc00[i]=0.f; acc01[i]=0.f; acc10[i]=0.f; acc11[i]=0.f; }

    #pragma unroll 2
    for (int kb = 0; kb < 16; ++kb) {
        const int k = kb * 16;
        bf16x8 a0, a1;
        if constexpr (AMODE == 1) {
            float4 x0 = *(const float4*)(A32 + a0off + k);
            float4 x1 = *(const float4*)(A32 + a0off + k + 4);
            float4 y0 = *(const float4*)(A32 + a1off + k);
            float4 y1 = *(const float4*)(A32 + a1off + k + 4);
            a0 = cvt8(x0, x1);
            a1 = cvt8(y0, y1);
        } else {
            a0 = *(const bf16x8*)(A16 + a0off + k);
            a1 = *(const bf16x8*)(A16 + a1off + k);
        }
        bf16x8 b0 = *(const bf16x8*)(b0p + k);
        bf16x8 b1 = *(const bf16x8*)(b1p + k);
        acc00 = MFMA32(a0, b0, acc00);
        acc01 = MFMA32(a0, b1, acc01);
        acc10 = MFMA32(a1, b0, acc10);
        acc11 = MFMA32(a1, b1, acc11);
    }

    // C/D layout (verified m74/m101): col = l31, row = (r&3)+8*(r>>2)+4*hi
    #pragma unroll
    for (int mt = 0; mt < 2; ++mt) {
        #pragma unroll
        for (int nt = 0; nt < 2; ++nt) {
            const f32x16 v = mt ? (nt ? acc11 : acc10) : (nt ? acc01 : acc00);
            const int col = nbase + nt * 32 + l31;
            const float bb = F32OUT ? bo[col] : 0.f;
            #pragma unroll
            for (int r = 0; r < 16; ++r) {
                const int row = mbase + mt * 32 + (r & 3) + 8 * (r >> 2) + 4 * hi;
                if (F32OUT) Cf[(size_t)row * ntot + col] = v[r] + bb;
                else        Cb[(size_t)row * ntot + col] = (bf16)v[r];
            }
        }
    }
}

// Block->tile remap: m = b&255, n = b>>8.  All n-variants of an A-strip share
// bid%8 (same XCD, 256 apart -> co-resident) -> A-strip HBM-read once.
__global__ __launch_bounds__(256) void proj_kernel(
    const float* __restrict__ qf, const float* __restrict__ kvf,
    const bf16* __restrict__ Wqg, const bf16* __restrict__ Wkv,
    bf16* __restrict__ QG, bf16* __restrict__ KV)
{
    int bid = blockIdx.x;
    bool sel = bid >= 1024;
    int b = sel ? bid - 1024 : bid;
    int m0 = (b & 255) * 128, n0 = (b >> 8) * 128;
    sgemm_core<1, false>(sel ? kvf : qf, sel ? Wkv : Wqg,
                         sel ? KV : QG, nullptr, nullptr, m0, n0, 512);
}

__global__ __launch_bounds__(256) void outproj_kernel(
    const bf16* __restrict__ OG, const bf16* __restrict__ Wo,
    const float* __restrict__ bo, float* __restrict__ out)
{
    int b = blockIdx.x;
    int m0 = (b & 255) * 128, n0 = (b >> 8) * 128;
    sgemm_core<0, true>(OG, Wo, nullptr, out, bo, m0, n0, 256);
}

// ================= attention per (s,h): 256 threads, 4 waves ====================
// Swapped QK^T (S^T = mfma(K, Q)): lane owns ONE q-row (q = lc), 64 k's.
// Softmax in-register (base-2, log2e pre-folded); P -> PV B-operand via
// cvt_pk + permlane32_swap + permlane16_swap; never touches LDS.
// QK^T in two 8-kt halves (MFMA 8 -> exp/pack 8) to cap sc live range; fence
// between halves allows VALU/SALU to cross but pins MFMA/DS (round-2 lesson:
// unconstrained -> VGPR 160 -> occupancy cliff; round-1 lesson: forcing
// occupancy via launch_bounds -> scratch spill; round-6 lesson: hoisting all 4
// qf loads -> VGPR 80, occupancy 37->23%, dur +3us -> reverted to per-p load).
// Block map: h = bid>>7, s = bid&127 -> XCD(bid%8) = s%8: all 8 h's of a row-s
// share one XCD's L2 (QG/KV lines fetched once); biasT 2 MB/XCD fits 4 MB L2.
// LDS: mask[256]f32 @0 | Ks[256][40]bf16 @1024 | Vt[32][264]bf16 @21504
#define A_OFF_MASK 0
#define A_OFF_K    1024
#define A_OFF_VT   21504
#define A_LDS_TOT  (21504 + 32 * 264 * 2)   // 38400 B -> 4 blocks/CU (LDS limit)

__global__ __launch_bounds__(256) void attn_kernel(
    const bf16* __restrict__ QG, const bf16* __restrict__ KV,
    const float* __restrict__ biasT, const float* __restrict__ bias_mask,
    const float* __restrict__ b_gL, bf16* __restrict__ OG)
{
    __shared__ __align__(16) char smem[A_LDS_TOT];
    float* maskadd = (float*)(smem + A_OFF_MASK);
    bf16*  Ks      = (bf16*)(smem + A_OFF_K);
    bf16*  Vt      = (bf16*)(smem + A_OFF_VT);

    const int tid  = threadIdx.x;
    const int wave = tid >> 6, lane = tid & 63;
    const int quad = lane >> 4, lc = lane & 15;
    const int h = blockIdx.x >> 7;       // all h of same s -> same XCD (bid%8 = s%8)
    const int s = blockIdx.x & 127;

    // ---- stage mask, K, V^T ----
    maskadd[tid] = (bias_mask[s * 256 + tid] - 1.0f) * (1e9f * L2E);
    {
        const bf16* kvrow = KV + (size_t)(s * 256 + tid) * 512 + h * 32;
        #pragma unroll
        for (int j = 0; j < 4; ++j)
            *(bf16x8*)(Ks + tid * 40 + j * 8) = *(const bf16x8*)(kvrow + j * 8);
        bf16x8 vx[4];
        #pragma unroll
        for (int j = 0; j < 4; ++j) vx[j] = *(const bf16x8*)(kvrow + 256 + j * 8);
        #pragma unroll
        for (int d = 0; d < 32; ++d)
            Vt[d * 264 + tid] = vx[d >> 3][d & 7];
    }
    __syncthreads();

    // gate bias (base-2 scaled), hoisted
    const f32x4 bg0 = *(const f32x4*)(b_gL + h * 32 + quad * 4);
    const f32x4 bg1 = *(const f32x4*)(b_gL + h * 32 + 16 + quad * 4);

    #pragma unroll 1
    for (int p = 0; p < 4; ++p) {
        const int q0 = (wave * 4 + p) * 16;

        // B-operand Q^T: lane holds Q[q0+lc][quad*8+j]
        bf16x8 qf = *(const bf16x8*)(QG + (size_t)(s * 256 + q0 + lc) * 512 + h * 32 + quad * 8);

        // S^T[k][q] in two 8-kt halves to cap sc live range (VGPR <= 128).
        const float* bT = biasT + (((size_t)h * 256 + q0 + lc) << 8) + quad * 4;
        u32x2 cw[16];
        float sum = 0.f;
        #pragma unroll
        for (int half = 0; half < 2; ++half) {
            f32x4 sc[8];
            #pragma unroll
            for (int k8 = 0; k8 < 8; ++k8) {
                const int kt = half * 8 + k8;
                bf16x8 kf = *(const bf16x8*)(Ks + (kt * 16 + lc) * 40 + quad * 8);
                f32x4 z = {0.f, 0.f, 0.f, 0.f};
                sc[k8] = MFMA16(kf, qf, z);
            }
            #pragma unroll
            for (int k8 = 0; k8 < 8; ++k8) {
                const int kt = half * 8 + k8;
                f32x4 bv = *(const f32x4*)(bT + kt * 16);
                f32x4 mv = *(const f32x4*)(maskadd + kt * 16 + quad * 4);
                f32x4 t = sc[k8] + bv + mv;       // packed f32 adds
                float e0 = fexp2(t[0]);
                float e1 = fexp2(t[1]);
                float e2 = fexp2(t[2]);
                float e3 = fexp2(t[3]);
                sum += (e0 + e1) + (e2 + e3);
                cw[kt] = u32x2{pk2(e0, e1), pk2(e2, e3)};
            }
            // VALU|SALU may cross (exp sinks into next half's MFMA slots);
            // MFMA/DS pinned -> sc live range stays one half.
            __builtin_amdgcn_sched_barrier(0x6);
        }

        // gate loads issued BEFORE PV: their latency hides under 16 MFMAs
        const bf16* gp = QG + (size_t)(s * 256 + q0 + lc) * 512 + 256 + h * 32 + quad * 4;
        bf16x4 gv0 = *(const bf16x4*)(gp);
        bf16x4 gv1 = *(const bf16x4*)(gp + 16);

        // PV as O^T = V^T @ P^T.  B-frag for chunk ks needs lane(quad q') to hold
        // P[q=lc][ks*32 + 8q' + j], j=0..7.  Built via 2x2 lane-group transposes:
        // {r0,r2}=pl16swap(pl32swap(c0,c2)), {r1,r3}=pl16swap(pl32swap(c1,c3)).
        f32x4 o0 = {0.f, 0.f, 0.f, 0.f}, o1 = {0.f, 0.f, 0.f, 0.f};
        #pragma unroll
        for (int ks = 0; ks < 8; ++ks) {
            u32 c0 = cw[2 * ks].x,     c1 = cw[2 * ks].y;
            u32 c2 = cw[2 * ks + 1].x, c3 = cw[2 * ks + 1].y;
            u32x2 s02 = __builtin_amdgcn_permlane32_swap(c0, c2, false, false);
            u32x2 s13 = __builtin_amdgcn_permlane32_swap(c1, c3, false, false);
            u32x2 e02 = __builtin_amdgcn_permlane16_swap(s02.x, s02.y, false, false);
            u32x2 e13 = __builtin_amdgcn_permlane16_swap(s13.x, s13.y, false, false);
            u32x4 pw = {e02.x, e13.x, e02.y, e13.y};
            bf16x8 pf = __builtin_bit_cast(bf16x8, pw);
            bf16x8 v0 = *(const bf16x8*)(Vt + lc * 264 + ks * 32 + quad * 8);
            bf16x8 v1 = *(const bf16x8*)(Vt + (16 + lc) * 264 + ks * 32 + quad * 8);
            o0 = MFMA16(v0, pf, o0);
            o1 = MFMA16(v1, pf, o1);
        }

        // row-sum reduce deferred to epilogue (inv only needed here)
        sum += __shfl_xor(sum, 16, 64);
        sum += __shfl_xor(sum, 32, 64);
        const float inv = frcp(sum);

        // epilogue: lane holds O^T[d = nt*16 + quad*4 + rr][q = lc]
        bf16* op = OG + (size_t)(s * 256 + q0 + lc) * 256 + h * 32 + quad * 4;
        #pragma unroll
        for (int nt = 0; nt < 2; ++nt) {
            f32x4 ov = nt ? o1 : o0;
            f32x4 bg = nt ? bg1 : bg0;
            bf16x4 gv = nt ? gv1 : gv0;
            bf16x4 ob;
            #pragma unroll
            for (int rr = 0; rr < 4; ++rr) {
                float e = fexp2(-((float)gv[rr] + bg[rr]));   // base-2 sigmoid
                float g = frcp(1.0f + e);
                ob[rr] = (bf16)(ov[rr] * (inv * g));
            }
            *(bf16x4*)(op + nt * 16) = ob;
        }
    }
}

// ================= launch =================
extern "C" void kernel_launch(void* const* d_in, const int* in_sizes, int n_in,
                              void* d_out, int out_size, void* d_ws, size_t ws_size,
                              hipStream_t stream)
{
    (void)in_sizes; (void)n_in; (void)out_size; (void)ws_size;
    const float* q    = (const float*)d_in[0];
    const float* kv   = (const float*)d_in[1];
    const float* bias = (const float*)d_in[2];
    const float* mask = (const float*)d_in[3];
    const float* w_q  = (const float*)d_in[4];
    const float* w_k  = (const float*)d_in[5];
    const float* w_v  = (const float*)d_in[6];
    const float* w_g  = (const float*)d_in[7];
    const float* b_g  = (const float*)d_in[8];
    const float* w_o  = (const float*)d_in[9];
    const float* b_o  = (const float*)d_in[10];
    float* out = (float*)d_out;

    char* ws = (char*)d_ws;
    bf16*  OG    = (bf16*)(ws + 0);           // 16.78 MB
    bf16*  QG    = (bf16*)(ws + 33554432);    // 33.55 MB  [32768][512] = [Q*norm | G*l2e]
    bf16*  KV    = (bf16*)(ws + 67108864);    // 33.55 MB  [32768][512] = [K | V]
    float* biasT = (float*)(ws + 100663296);  //  2.10 MB  [h][q][k] * log2e
    bf16*  Wqg   = (bf16*)(ws + 102760448);   //  0.26 MB
    bf16*  Wkv   = (bf16*)(ws + 103022592);   //  0.26 MB
    bf16*  Wo    = (bf16*)(ws + 103284736);   //  0.13 MB
    float* b_gL  = (float*)(ws + 103415808);  //  1 KB     b_g * log2e

    prep_kernel<<<256, 256, 0, stream>>>(bias, w_q, w_k, w_v, w_g, w_o, b_g,
                                         biasT, Wqg, Wkv, Wo, b_gL);
    proj_kernel<<<2048, 256, 0, stream>>>(q, kv, Wqg, Wkv, QG, KV);
    attn_kernel<<<1024, 256, 0, stream>>>(QG, KV, biasT, mask, b_gL, OG);
    outproj_kernel<<<512, 256, 0, stream>>>(OG, Wo, b_o, out);
}

// Round 8
// 240.543 us; speedup vs baseline: 1.1622x; 1.1622x over previous
//
#include <hip/hip_runtime.h>

typedef __bf16 bf16;
typedef __bf16 bf16x8 __attribute__((ext_vector_type(8)));
typedef __bf16 bf16x4 __attribute__((ext_vector_type(4)));
typedef float  f32x4  __attribute__((ext_vector_type(4)));
typedef unsigned int u32;
typedef unsigned int u32x2 __attribute__((ext_vector_type(2)));
typedef unsigned int u32x4 __attribute__((ext_vector_type(4)));
typedef unsigned short u16;

#define MFMA16(a, b, c) __builtin_amdgcn_mfma_f32_16x16x32_bf16((a), (b), (c), 0, 0, 0)
#define L2E 1.4426950408889634f

// B=1, S=128, R=256, C=256, H=8, Ca=32.  M = S*R = 32768, K = 256.

// ---- async global->LDS, 16 B per lane (guide §5: width=16) ----
typedef __attribute__((address_space(3))) u32 lds_u32;
typedef const __attribute__((address_space(1))) u32 glob_u32;
__device__ __forceinline__ void gll16(const void* g, void* l) {
    __builtin_amdgcn_global_load_lds((glob_u32*)g, (lds_u32*)l, 16, 0, 0);
}

// pack two f32 -> one u32 of 2 bf16 (lo, hi)
__device__ __forceinline__ u32 pk2(float lo, float hi) {
    u16 a = __builtin_bit_cast(u16, (bf16)lo);
    u16 b = __builtin_bit_cast(u16, (bf16)hi);
    return ((u32)b << 16) | (u32)a;
}

__device__ __forceinline__ bf16x8 cvt8(float4 a, float4 b) {
    bf16x8 t;
    t[0]=(bf16)a.x; t[1]=(bf16)a.y; t[2]=(bf16)a.z; t[3]=(bf16)a.w;
    t[4]=(bf16)b.x; t[5]=(bf16)b.y; t[6]=(bf16)b.z; t[7]=(bf16)b.w;
    return t;
}

__device__ __forceinline__ float fexp2(float x) {
#if __has_builtin(__builtin_amdgcn_exp2f)
    return __builtin_amdgcn_exp2f(x);
#else
    return exp2f(x);
#endif
}
__device__ __forceinline__ float frcp(float x) {
#if __has_builtin(__builtin_amdgcn_rcpf)
    return __builtin_amdgcn_rcpf(x);
#else
    return 1.0f / x;
#endif
}

// ================= prep: bias transpose + weight transposes only ==============
__global__ __launch_bounds__(256) void prep_kernel(
    const float* __restrict__ bias,
    const float* __restrict__ w_q, const float* __restrict__ w_k,
    const float* __restrict__ w_v, const float* __restrict__ w_g,
    const float* __restrict__ w_o, const float* __restrict__ b_g,
    float* __restrict__ biasT,
    bf16* __restrict__ Wqg, bf16* __restrict__ Wkv, bf16* __restrict__ Wo,
    float* __restrict__ b_gL)
{
    // 1/sqrt(32) * log2(e): softmax computed in base-2 (exp2)
    const float norm = 0.17677669529663687f * L2E;
    const int gid = blockIdx.x * 256 + threadIdx.x;
    const int gsz = gridDim.x * 256;

    // biasT[h][q][k] <- bias[q][k][h] * log2e  (coalesced writes)
    for (int u = gid; u < 524288; u += gsz) {
        int h = u >> 16, qq = (u >> 8) & 255, kk = u & 255;
        biasT[u] = bias[(((qq << 8) + kk) << 3) + h] * L2E;
    }
    // Wqg[n][k]: n<256 -> w_q[k][n]*norm ; else w_g[k][n-256]*log2e (gate in base-2)
    for (int u = gid; u < 131072; u += gsz) {
        int n = u >> 8, k = u & 255;
        float v = (n < 256) ? w_q[k * 256 + n] * norm : w_g[k * 256 + (n - 256)] * L2E;
        Wqg[u] = (bf16)v;
    }
    // Wkv[n][k]: n<256 -> w_k[k][n] ; else w_v[k][n-256]
    for (int u = gid; u < 131072; u += gsz) {
        int n = u >> 8, k = u & 255;
        float v = (n < 256) ? w_k[k * 256 + n] : w_v[k * 256 + (n - 256)];
        Wkv[u] = (bf16)v;
    }
    // Wo[n][k] = w_o[k][n]   ([H*Ca][C] -> [C][H*Ca])
    for (int u = gid; u < 65536; u += gsz) {
        int n = u >> 8, k = u & 255;
        Wo[u] = (bf16)w_o[k * 256 + n];
    }
    // b_gL = b_g * log2e
    for (int u = gid; u < 256; u += gsz) b_gL[u] = b_g[u] * L2E;
}

// ================= proj GEMM: QG/KV = [q|kv] @ W^T  (round-6 core, best known) =
// 128x128 tile, 256 threads, BK=32, dbuf via 4 distinct __shared__ objects +
// fully unrolled steps (round-5 lesson: runtime LDS base defeats alias analysis
// -> silent serialization).  Round-7 lesson: do NOT drop gll16 staging — the
// streaming per-lane 16B loads at 1KB stride cost 64 discrete requests/wave
// (proj 55->114us).  gll16's contiguous 4KB bursts are the BW carrier.
__device__ __forceinline__ void proj_core(
    const float* __restrict__ A32, const bf16* __restrict__ Bw,
    bf16* __restrict__ Cb, int m0, int n0)
{
    __shared__ __align__(16) bf16 As0[128 * 32], Bs0[128 * 32];
    __shared__ __align__(16) bf16 As1[128 * 32], Bs1[128 * 32];

    const int tid  = threadIdx.x;
    const int lane = tid & 63, wave = tid >> 6;
    const int quad = lane >> 4, lc = lane & 15;
    const int wr = wave >> 1, wc = wave & 1;

    const int r0 = tid >> 2, p0 = tid & 3;
    const size_t offA0 = (size_t)(m0 + r0) * 256 + p0 * 8;
    const size_t offA1 = (size_t)(m0 + 64 + r0) * 256 + p0 * 8;
    const bf16* gB0 = Bw + (size_t)(n0 + r0) * 256 + p0 * 8;
    const bf16* gB1 = Bw + (size_t)(n0 + 64 + r0) * 256 + p0 * 8;

    f32x4 acc[4][4];
    #pragma unroll
    for (int i = 0; i < 4; ++i)
        #pragma unroll
        for (int j = 0; j < 4; ++j) acc[i][j] = f32x4{0.f, 0.f, 0.f, 0.f};

    // prologue: stage tile 0 -> buf 0
    {
        float4 x0 = *(const float4*)(A32 + offA0);
        float4 x1 = *(const float4*)(A32 + offA0 + 4);
        float4 y0 = *(const float4*)(A32 + offA1);
        float4 y1 = *(const float4*)(A32 + offA1 + 4);
        *(bf16x8*)(As0 + tid * 8)         = cvt8(x0, x1);
        *(bf16x8*)(As0 + (tid + 256) * 8) = cvt8(y0, y1);
        gll16(gB0, Bs0 + tid * 8);
        gll16(gB1, Bs0 + (tid + 256) * 8);
    }
    __syncthreads();

    auto step = [&](const bf16* Ac, const bf16* Bc, bf16* An, bf16* Bn,
                    int kn, bool pf) {
        float4 x0, x1, y0, y1;
        if (pf) {
            x0 = *(const float4*)(A32 + offA0 + kn);
            x1 = *(const float4*)(A32 + offA0 + kn + 4);
            y0 = *(const float4*)(A32 + offA1 + kn);
            y1 = *(const float4*)(A32 + offA1 + kn + 4);
            gll16(gB0 + kn, Bn + tid * 8);
            gll16(gB1 + kn, Bn + (tid + 256) * 8);
        }
        __builtin_amdgcn_sched_barrier(0);  // staging stays above, compute below

        bf16x8 aF[4], bF[4];
        #pragma unroll
        for (int mt = 0; mt < 4; ++mt)
            aF[mt] = *(const bf16x8*)(Ac + (wr * 64 + mt * 16 + lc) * 32 + quad * 8);
        #pragma unroll
        for (int nt = 0; nt < 4; ++nt)
            bF[nt] = *(const bf16x8*)(Bc + (wc * 64 + nt * 16 + lc) * 32 + quad * 8);
        #pragma unroll
        for (int mt = 0; mt < 4; ++mt)
            #pragma unroll
            for (int nt = 0; nt < 4; ++nt)
                acc[mt][nt] = MFMA16(aF[mt], bF[nt], acc[mt][nt]);

        if (pf) {
            *(bf16x8*)(An + tid * 8)         = cvt8(x0, x1);
            *(bf16x8*)(An + (tid + 256) * 8) = cvt8(y0, y1);
        }
        __syncthreads();
    };

    step(As0, Bs0, As1, Bs1,  32, true);
    step(As1, Bs1, As0, Bs0,  64, true);
    step(As0, Bs0, As1, Bs1,  96, true);
    step(As1, Bs1, As0, Bs0, 128, true);
    step(As0, Bs0, As1, Bs1, 160, true);
    step(As1, Bs1, As0, Bs0, 192, true);
    step(As0, Bs0, As1, Bs1, 224, true);
    step(As1, Bs1, As0, Bs0,   0, false);

    #pragma unroll
    for (int mt = 0; mt < 4; ++mt) {
        #pragma unroll
        for (int nt = 0; nt < 4; ++nt) {
            const int row = m0 + wr * 64 + mt * 16 + quad * 4;
            const int col = n0 + wc * 64 + nt * 16 + lc;
            #pragma unroll
            for (int rr = 0; rr < 4; ++rr)
                Cb[(size_t)(row + rr) * 512 + col] = (bf16)acc[mt][nt][rr];
        }
    }
}

// Block->tile remap: m = b&255, n = b>>8 — A-strip's n-variants share the XCD.
__global__ __launch_bounds__(256) void proj_kernel(
    const float* __restrict__ qf, const float* __restrict__ kvf,
    const bf16* __restrict__ Wqg, const bf16* __restrict__ Wkv,
    bf16* __restrict__ QG, bf16* __restrict__ KV)
{
    int bid = blockIdx.x;
    bool sel = bid >= 1024;
    int b = sel ? bid - 1024 : bid;
    int m0 = (b & 255) * 128, n0 = (b >> 8) * 128;
    proj_core(sel ? kvf : qf, sel ? Wkv : Wqg, sel ? KV : QG, m0, n0);
}

// ============ fused attention + out-projection: per (s, quarter) ==============
// Block = 256 thr (4 waves), grid 512: quarter = bid>>7, s = bid&127 (s%8 = XCD
// -> the 4 quarter-blocks of an s co-locate on one XCD: K/V/QG L2-shared).
// Each wave owns 16 q-rows.  Loop h = 0..7 (FULLY unrolled for static ogr[]
// indexing, rule #20): stage Ks/Vt(h); swapped QK^T (two 8-kt halves, base-2
// softmax, in-register); PV via cvt_pk+permlane transposes; gate; then a SECOND
// permlane pass converts gated O^T (quad-interleaved d) into the out-projection
// A-fragment layout OG[q=lc][h*32 + quad*8 + j] — one u32x4/h held in regs.
// After the h-loop: out[rows][256] = ogr @ Wo directly from registers (zero
// A-loads; Wo 0.13MB L2-hot).  Eliminates the OG HBM round-trip (33.5 MB), the
// outproj kernel (~30-40us latency-bound), and one launch gap.
// LDS: mask[256]f32 @0 | Ks[256][40]bf16 @1024 | Vt[32][264]bf16 @21504
#define A_OFF_MASK 0
#define A_OFF_K    1024
#define A_OFF_VT   21504
#define A_LDS_TOT  (21504 + 32 * 264 * 2)   // 38400 B

__global__ __launch_bounds__(256) void attn_out_kernel(
    const bf16* __restrict__ QG, const bf16* __restrict__ KV,
    const float* __restrict__ biasT, const float* __restrict__ bias_mask,
    const float* __restrict__ b_gL, const bf16* __restrict__ Wo,
    const float* __restrict__ b_o, float* __restrict__ out)
{
    __shared__ __align__(16) char smem[A_LDS_TOT];
    float* maskadd = (float*)(smem + A_OFF_MASK);
    bf16*  Ks      = (bf16*)(smem + A_OFF_K);
    bf16*  Vt      = (bf16*)(smem + A_OFF_VT);

    const int tid  = threadIdx.x;
    const int wave = tid >> 6, lane = tid & 63;
    const int quad = lane >> 4, lc = lane & 15;
    const int quarter = blockIdx.x >> 7;
    const int s = blockIdx.x & 127;
    const int rbase = quarter * 64 + wave * 16;      // q-row base (within s) for this wave

    maskadd[tid] = (bias_mask[s * 256 + tid] - 1.0f) * (1e9f * L2E);

    u32x4 ogr[8];   // per-h out-proj A-fragments (static-indexed: h-loop unrolled)

    #pragma unroll
    for (int h = 0; h < 8; ++h) {
        if (h) __syncthreads();              // waves done reading Ks/Vt of h-1
        {   // stage K rows + V^T for (s,h): thread = k-row
            const bf16* kvrow = KV + (size_t)(s * 256 + tid) * 512 + h * 32;
            #pragma unroll
            for (int j = 0; j < 4; ++j)
                *(bf16x8*)(Ks + tid * 40 + j * 8) = *(const bf16x8*)(kvrow + j * 8);
            bf16x8 vx[4];
            #pragma unroll
            for (int j = 0; j < 4; ++j) vx[j] = *(const bf16x8*)(kvrow + 256 + j * 8);
            #pragma unroll
            for (int d = 0; d < 32; ++d)
                Vt[d * 264 + tid] = vx[d >> 3][d & 7];
        }
        __syncthreads();

        // B-operand Q^T: lane holds Q[rbase+lc][quad*8+j]
        const size_t qrow = (size_t)(s * 256 + rbase + lc);
        bf16x8 qf = *(const bf16x8*)(QG + qrow * 512 + h * 32 + quad * 8);

        // S^T[k][q] in two 8-kt halves (caps sc live range)
        const float* bT = biasT + (((size_t)(h * 256 + rbase + lc)) << 8) + quad * 4;
        u32x2 cw[16];
        float sum = 0.f;
        #pragma unroll
        for (int half = 0; half < 2; ++half) {
            f32x4 sc[8];
            #pragma unroll
            for (int k8 = 0; k8 < 8; ++k8) {
                const int kt = half * 8 + k8;
                bf16x8 kf = *(const bf16x8*)(Ks + (kt * 16 + lc) * 40 + quad * 8);
                f32x4 z = {0.f, 0.f, 0.f, 0.f};
                sc[k8] = MFMA16(kf, qf, z);
            }
            #pragma unroll
            for (int k8 = 0; k8 < 8; ++k8) {
                const int kt = half * 8 + k8;
                f32x4 bv = *(const f32x4*)(bT + kt * 16);
                f32x4 mv = *(const f32x4*)(maskadd + kt * 16 + quad * 4);
                f32x4 t = sc[k8] + bv + mv;
                float e0 = fexp2(t[0]);
                float e1 = fexp2(t[1]);
                float e2 = fexp2(t[2]);
                float e3 = fexp2(t[3]);
                sum += (e0 + e1) + (e2 + e3);
                cw[kt] = u32x2{pk2(e0, e1), pk2(e2, e3)};
            }
            __builtin_amdgcn_sched_barrier(0x6);  // VALU/SALU may cross; MFMA/DS pinned
        }

        // gate loads issued before PV (latency hides under 16 MFMAs)
        const bf16* gp = QG + qrow * 512 + 256 + h * 32 + quad * 4;
        bf16x4 gv0 = *(const bf16x4*)(gp);
        bf16x4 gv1 = *(const bf16x4*)(gp + 16);

        // PV: O^T = V^T @ P^T (P fragment built via permlane 2x2 transposes)
        f32x4 o0 = {0.f, 0.f, 0.f, 0.f}, o1 = {0.f, 0.f, 0.f, 0.f};
        #pragma unroll
        for (int ks = 0; ks < 8; ++ks) {
            u32 c0 = cw[2 * ks].x,     c1 = cw[2 * ks].y;
            u32 c2 = cw[2 * ks + 1].x, c3 = cw[2 * ks + 1].y;
            u32x2 s02 = __builtin_amdgcn_permlane32_swap(c0, c2, false, false);
            u32x2 s13 = __builtin_amdgcn_permlane32_swap(c1, c3, false, false);
            u32x2 e02 = __builtin_amdgcn_permlane16_swap(s02.x, s02.y, false, false);
            u32x2 e13 = __builtin_amdgcn_permlane16_swap(s13.x, s13.y, false, false);
            u32x4 pw = {e02.x, e13.x, e02.y, e13.y};
            bf16x8 pf = __builtin_bit_cast(bf16x8, pw);
            bf16x8 v0 = *(const bf16x8*)(Vt + lc * 264 + ks * 32 + quad * 8);
            bf16x8 v1 = *(const bf16x8*)(Vt + (16 + lc) * 264 + ks * 32 + quad * 8);
            o0 = MFMA16(v0, pf, o0);
            o1 = MFMA16(v1, pf, o1);
        }

        sum += __shfl_xor(sum, 16, 64);
        sum += __shfl_xor(sum, 32, 64);
        const float inv = frcp(sum);

        // gate + normalize, then permute gated O^T into the out-proj A-frag:
        // input per lane(quad): a,b = d=quad*4+{0,1},{2,3}; c,d = 16+quad*4+...
        // -> same chunkxquad structure as the P path: identical swap sequence
        // yields lane(quad') = OG[q=lc][h*32 + quad'*8 + j], j=0..7.
        const f32x4 bg0 = *(const f32x4*)(b_gL + h * 32 + quad * 4);
        const f32x4 bg1 = *(const f32x4*)(b_gL + h * 32 + 16 + quad * 4);
        float f0[4], f1[4];
        #pragma unroll
        for (int rr = 0; rr < 4; ++rr) {
            float g0 = frcp(1.0f + fexp2(-((float)gv0[rr] + bg0[rr])));
            float g1 = frcp(1.0f + fexp2(-((float)gv1[rr] + bg1[rr])));
            f0[rr] = o0[rr] * (inv * g0);
            f1[rr] = o1[rr] * (inv * g1);
        }
        u32 a = pk2(f0[0], f0[1]), b = pk2(f0[2], f0[3]);
        u32 c = pk2(f1[0], f1[1]), d = pk2(f1[2], f1[3]);
        u32x2 s02 = __builtin_amdgcn_permlane32_swap(a, c, false, false);
        u32x2 s13 = __builtin_amdgcn_permlane32_swap(b, d, false, false);
        u32x2 e02 = __builtin_amdgcn_permlane16_swap(s02.x, s02.y, false, false);
        u32x2 e13 = __builtin_amdgcn_permlane16_swap(s13.x, s13.y, false, false);
        ogr[h] = u32x4{e02.x, e13.x, e02.y, e13.y};
        __builtin_amdgcn_sched_barrier(0);   // iteration boundary: cap reg pressure
    }

    // ---- fused out-projection: out[16 rows][256] = OG(regs) @ Wo^T + b_o ----
    f32x4 acc[16];
    #pragma unroll
    for (int nt = 0; nt < 16; ++nt) acc[nt] = f32x4{0.f, 0.f, 0.f, 0.f};
    #pragma unroll
    for (int ks = 0; ks < 8; ++ks) {
        bf16x8 aF = __builtin_bit_cast(bf16x8, ogr[ks]);   // OG[q=lc][ks*32+quad*8+j]
        #pragma unroll
        for (int nt = 0; nt < 16; ++nt) {
            bf16x8 bF = *(const bf16x8*)(Wo + (size_t)(nt * 16 + lc) * 256 + ks * 32 + quad * 8);
            acc[nt] = MFMA16(aF, bF, acc[nt]);
        }
    }
    // C/D: row = rbase + quad*4 + rr, col = nt*16 + lc
    float* op = out + (size_t)(s * 256 + rbase + quad * 4) * 256;
    #pragma unroll
    for (int nt = 0; nt < 16; ++nt) {
        const float bb = b_o[nt * 16 + lc];
        #pragma unroll
        for (int rr = 0; rr < 4; ++rr)
            op[(size_t)rr * 256 + nt * 16 + lc] = acc[nt][rr] + bb;
    }
}

// ================= launch =================
extern "C" void kernel_launch(void* const* d_in, const int* in_sizes, int n_in,
                              void* d_out, int out_size, void* d_ws, size_t ws_size,
                              hipStream_t stream)
{
    (void)in_sizes; (void)n_in; (void)out_size; (void)ws_size;
    const float* q    = (const float*)d_in[0];
    const float* kv   = (const float*)d_in[1];
    const float* bias = (const float*)d_in[2];
    const float* mask = (const float*)d_in[3];
    const float* w_q  = (const float*)d_in[4];
    const float* w_k  = (const float*)d_in[5];
    const float* w_v  = (const float*)d_in[6];
    const float* w_g  = (const float*)d_in[7];
    const float* b_g  = (const float*)d_in[8];
    const float* w_o  = (const float*)d_in[9];
    const float* b_o  = (const float*)d_in[10];
    float* out = (float*)d_out;

    char* ws = (char*)d_ws;
    bf16*  QG    = (bf16*)(ws + 33554432);    // 33.55 MB  [32768][512] = [Q*norm | G*l2e]
    bf16*  KV    = (bf16*)(ws + 67108864);    // 33.55 MB  [32768][512] = [K | V]
    float* biasT = (float*)(ws + 100663296);  //  2.10 MB  [h][q][k] * log2e
    bf16*  Wqg   = (bf16*)(ws + 102760448);   //  0.26 MB
    bf16*  Wkv   = (bf16*)(ws + 103022592);   //  0.26 MB
    bf16*  Wo    = (bf16*)(ws + 103284736);   //  0.13 MB
    float* b_gL  = (float*)(ws + 103415808);  //  1 KB     b_g * log2e

    prep_kernel<<<256, 256, 0, stream>>>(bias, w_q, w_k, w_v, w_g, w_o, b_g,
                                         biasT, Wqg, Wkv, Wo, b_gL);
    proj_kernel<<<2048, 256, 0, stream>>>(q, kv, Wqg, Wkv, QG, KV);
    attn_out_kernel<<<512, 256, 0, stream>>>(QG, KV, biasT, mask, b_gL, Wo, b_o, out);
}

// Round 9
// 208.633 us; speedup vs baseline: 1.3400x; 1.1529x over previous
//
#include <hip/hip_runtime.h>

typedef __bf16 bf16;
typedef __bf16 bf16x8 __attribute__((ext_vector_type(8)));
typedef __bf16 bf16x4 __attribute__((ext_vector_type(4)));
typedef float  f32x4  __attribute__((ext_vector_type(4)));
typedef unsigned int u32;
typedef unsigned int u32x2 __attribute__((ext_vector_type(2)));
typedef unsigned int u32x4 __attribute__((ext_vector_type(4)));
typedef unsigned short u16;

#define MFMA16(a, b, c) __builtin_amdgcn_mfma_f32_16x16x32_bf16((a), (b), (c), 0, 0, 0)
#define L2E 1.4426950408889634f

// B=1, S=128, R=256, C=256, H=8, Ca=32.  M = S*R = 32768, K = 256.

// ---- async global->LDS, 16 B per lane ----
typedef __attribute__((address_space(3))) u32 lds_u32;
typedef const __attribute__((address_space(1))) u32 glob_u32;
__device__ __forceinline__ void gll16(const void* g, void* l) {
    __builtin_amdgcn_global_load_lds((glob_u32*)g, (lds_u32*)l, 16, 0, 0);
}

__device__ __forceinline__ u32 pk2(float lo, float hi) {
    u16 a = __builtin_bit_cast(u16, (bf16)lo);
    u16 b = __builtin_bit_cast(u16, (bf16)hi);
    return ((u32)b << 16) | (u32)a;
}

__device__ __forceinline__ bf16x8 cvt8(float4 a, float4 b) {
    bf16x8 t;
    t[0]=(bf16)a.x; t[1]=(bf16)a.y; t[2]=(bf16)a.z; t[3]=(bf16)a.w;
    t[4]=(bf16)b.x; t[5]=(bf16)b.y; t[6]=(bf16)b.z; t[7]=(bf16)b.w;
    return t;
}

__device__ __forceinline__ float fexp2(float x) {
#if __has_builtin(__builtin_amdgcn_exp2f)
    return __builtin_amdgcn_exp2f(x);
#else
    return exp2f(x);
#endif
}
__device__ __forceinline__ float frcp(float x) {
#if __has_builtin(__builtin_amdgcn_rcpf)
    return __builtin_amdgcn_rcpf(x);
#else
    return 1.0f / x;
#endif
}

// ================= prep: bias transpose + weight transposes only ==============
__global__ __launch_bounds__(256) void prep_kernel(
    const float* __restrict__ bias,
    const float* __restrict__ w_q, const float* __restrict__ w_k,
    const float* __restrict__ w_v, const float* __restrict__ w_g,
    const float* __restrict__ w_o, const float* __restrict__ b_g,
    float* __restrict__ biasT,
    bf16* __restrict__ Wqg, bf16* __restrict__ Wkv, bf16* __restrict__ Wo,
    float* __restrict__ b_gL)
{
    const float norm = 0.17677669529663687f * L2E;   // 1/sqrt(32)*log2e (base-2 softmax)
    const int gid = blockIdx.x * 256 + threadIdx.x;
    const int gsz = gridDim.x * 256;

    for (int u = gid; u < 524288; u += gsz) {        // biasT[h][q][k] * log2e
        int h = u >> 16, qq = (u >> 8) & 255, kk = u & 255;
        biasT[u] = bias[(((qq << 8) + kk) << 3) + h] * L2E;
    }
    for (int u = gid; u < 131072; u += gsz) {        // Wqg[n][k]
        int n = u >> 8, k = u & 255;
        float v = (n < 256) ? w_q[k * 256 + n] * norm : w_g[k * 256 + (n - 256)] * L2E;
        Wqg[u] = (bf16)v;
    }
    for (int u = gid; u < 131072; u += gsz) {        // Wkv[n][k]
        int n = u >> 8, k = u & 255;
        float v = (n < 256) ? w_k[k * 256 + n] : w_v[k * 256 + (n - 256)];
        Wkv[u] = (bf16)v;
    }
    for (int u = gid; u < 65536; u += gsz) {         // Wo[n][k]
        int n = u >> 8, k = u & 255;
        Wo[u] = (bf16)w_o[k * 256 + n];
    }
    for (int u = gid; u < 256; u += gsz) b_gL[u] = b_g[u] * L2E;
}

// ================= proj GEMM (round-6 core, best known: ~54us) ================
// 128x128 tile, BK=32, dbuf via 4 distinct __shared__ objects + unrolled steps.
// Round-7 lesson: keep gll16/contiguous-burst staging (streaming per-lane 16B
// loads at 1KB stride doubled the time).
__device__ __forceinline__ void proj_core(
    const float* __restrict__ A32, const bf16* __restrict__ Bw,
    bf16* __restrict__ Cb, int m0, int n0)
{
    __shared__ __align__(16) bf16 As0[128 * 32], Bs0[128 * 32];
    __shared__ __align__(16) bf16 As1[128 * 32], Bs1[128 * 32];

    const int tid  = threadIdx.x;
    const int lane = tid & 63, wave = tid >> 6;
    const int quad = lane >> 4, lc = lane & 15;
    const int wr = wave >> 1, wc = wave & 1;

    const int r0 = tid >> 2, p0 = tid & 3;
    const size_t offA0 = (size_t)(m0 + r0) * 256 + p0 * 8;
    const size_t offA1 = (size_t)(m0 + 64 + r0) * 256 + p0 * 8;
    const bf16* gB0 = Bw + (size_t)(n0 + r0) * 256 + p0 * 8;
    const bf16* gB1 = Bw + (size_t)(n0 + 64 + r0) * 256 + p0 * 8;

    f32x4 acc[4][4];
    #pragma unroll
    for (int i = 0; i < 4; ++i)
        #pragma unroll
        for (int j = 0; j < 4; ++j) acc[i][j] = f32x4{0.f, 0.f, 0.f, 0.f};

    {
        float4 x0 = *(const float4*)(A32 + offA0);
        float4 x1 = *(const float4*)(A32 + offA0 + 4);
        float4 y0 = *(const float4*)(A32 + offA1);
        float4 y1 = *(const float4*)(A32 + offA1 + 4);
        *(bf16x8*)(As0 + tid * 8)         = cvt8(x0, x1);
        *(bf16x8*)(As0 + (tid + 256) * 8) = cvt8(y0, y1);
        gll16(gB0, Bs0 + tid * 8);
        gll16(gB1, Bs0 + (tid + 256) * 8);
    }
    __syncthreads();

    auto step = [&](const bf16* Ac, const bf16* Bc, bf16* An, bf16* Bn,
                    int kn, bool pf) {
        float4 x0, x1, y0, y1;
        if (pf) {
            x0 = *(const float4*)(A32 + offA0 + kn);
            x1 = *(const float4*)(A32 + offA0 + kn + 4);
            y0 = *(const float4*)(A32 + offA1 + kn);
            y1 = *(const float4*)(A32 + offA1 + kn + 4);
            gll16(gB0 + kn, Bn + tid * 8);
            gll16(gB1 + kn, Bn + (tid + 256) * 8);
        }
        __builtin_amdgcn_sched_barrier(0);

        bf16x8 aF[4], bF[4];
        #pragma unroll
        for (int mt = 0; mt < 4; ++mt)
            aF[mt] = *(const bf16x8*)(Ac + (wr * 64 + mt * 16 + lc) * 32 + quad * 8);
        #pragma unroll
        for (int nt = 0; nt < 4; ++nt)
            bF[nt] = *(const bf16x8*)(Bc + (wc * 64 + nt * 16 + lc) * 32 + quad * 8);
        #pragma unroll
        for (int mt = 0; mt < 4; ++mt)
            #pragma unroll
            for (int nt = 0; nt < 4; ++nt)
                acc[mt][nt] = MFMA16(aF[mt], bF[nt], acc[mt][nt]);

        if (pf) {
            *(bf16x8*)(An + tid * 8)         = cvt8(x0, x1);
            *(bf16x8*)(An + (tid + 256) * 8) = cvt8(y0, y1);
        }
        __syncthreads();
    };

    step(As0, Bs0, As1, Bs1,  32, true);
    step(As1, Bs1, As0, Bs0,  64, true);
    step(As0, Bs0, As1, Bs1,  96, true);
    step(As1, Bs1, As0, Bs0, 128, true);
    step(As0, Bs0, As1, Bs1, 160, true);
    step(As1, Bs1, As0, Bs0, 192, true);
    step(As0, Bs0, As1, Bs1, 224, true);
    step(As1, Bs1, As0, Bs0,   0, false);

    #pragma unroll
    for (int mt = 0; mt < 4; ++mt) {
        #pragma unroll
        for (int nt = 0; nt < 4; ++nt) {
            const int row = m0 + wr * 64 + mt * 16 + quad * 4;
            const int col = n0 + wc * 64 + nt * 16 + lc;
            #pragma unroll
            for (int rr = 0; rr < 4; ++rr)
                Cb[(size_t)(row + rr) * 512 + col] = (bf16)acc[mt][nt][rr];
        }
    }
}

// XCD write/read alignment: attn reads QG/KV rows of s from XCD s%8.  Map the
// m-strip so the WRITER's XCD = (strip>>1)%8: strip = b3 | (b[2:0]<<1) | (b[7:4]<<4)
// (bijective per n-tile; XCD = bid%8 = b[2:0] = strip[3:1] = (strip>>1)&7 ✓).
__global__ __launch_bounds__(256) void proj_kernel(
    const float* __restrict__ qf, const float* __restrict__ kvf,
    const bf16* __restrict__ Wqg, const bf16* __restrict__ Wkv,
    bf16* __restrict__ QG, bf16* __restrict__ KV)
{
    int bid = blockIdx.x;
    bool sel = bid >= 1024;
    int b = bid & 1023;
    int strip = ((b >> 3) & 1) | ((b & 7) << 1) | (((b >> 4) & 15) << 4);
    int m0 = strip * 128, n0 = (b >> 8) * 128;
    proj_core(sel ? kvf : qf, sel ? Wkv : Wqg, sel ? KV : QG, m0, n0);
}

// ============ outproj: out[M][256] = OG[M][256] @ Wo[256][256]^T + b_o =========
// 64x128 tile, grid 1024 (round-8 ledger: old 512-block version was GRID-limited
// to 2 blocks/CU, ~30us vs 8us HBM floor).  LDS 24KB -> 4 blocks/CU at grid 4/CU.
// OG is 2.1 MB/XCD: attn wrote rows of s from XCD s%8, and it all FITS in that
// L2.  Map reader strip so XCD = (strip>>2)%8 = s%8 -> OG reads are same-XCD L2
// hits, never re-fetched from HBM.
__global__ __launch_bounds__(256) void outproj_kernel(
    const bf16* __restrict__ OG, const bf16* __restrict__ Wo,
    const float* __restrict__ bo, float* __restrict__ out)
{
    __shared__ __align__(16) bf16 As0[64 * 32], Bs0[128 * 32];
    __shared__ __align__(16) bf16 As1[64 * 32], Bs1[128 * 32];

    const int bid = blockIdx.x;
    const int x = bid & 7;
    const int strip = ((bid >> 3) & 3) | (x << 2) | (((bid >> 5) & 15) << 5);
    const int m0 = strip * 64, n0 = (bid >> 9) * 128;

    const int tid  = threadIdx.x;
    const int lane = tid & 63, wave = tid >> 6;
    const int quad = lane >> 4, lc = lane & 15;
    const int wr = wave >> 1, wc = wave & 1;   // wave tile: 32 x 64

    const int r0 = tid >> 2, p0 = tid & 3;     // r0: 0..63
    const bf16* gA  = OG + (size_t)(m0 + r0) * 256 + p0 * 8;
    const bf16* gB0 = Wo + (size_t)(n0 + r0) * 256 + p0 * 8;
    const bf16* gB1 = Wo + (size_t)(n0 + 64 + r0) * 256 + p0 * 8;

    f32x4 acc[2][4];
    #pragma unroll
    for (int i = 0; i < 2; ++i)
        #pragma unroll
        for (int j = 0; j < 4; ++j) acc[i][j] = f32x4{0.f, 0.f, 0.f, 0.f};

    gll16(gA,  As0 + tid * 8);
    gll16(gB0, Bs0 + tid * 8);
    gll16(gB1, Bs0 + (tid + 256) * 8);
    __syncthreads();

    auto step = [&](const bf16* Ac, const bf16* Bc, bf16* An, bf16* Bn,
                    int kn, bool pf) {
        if (pf) {
            gll16(gA + kn,  An + tid * 8);
            gll16(gB0 + kn, Bn + tid * 8);
            gll16(gB1 + kn, Bn + (tid + 256) * 8);
        }
        __builtin_amdgcn_sched_barrier(0);

        bf16x8 aF[2], bF[4];
        #pragma unroll
        for (int mt = 0; mt < 2; ++mt)
            aF[mt] = *(const bf16x8*)(Ac + (wr * 32 + mt * 16 + lc) * 32 + quad * 8);
        #pragma unroll
        for (int nt = 0; nt < 4; ++nt)
            bF[nt] = *(const bf16x8*)(Bc + (wc * 64 + nt * 16 + lc) * 32 + quad * 8);
        #pragma unroll
        for (int mt = 0; mt < 2; ++mt)
            #pragma unroll
            for (int nt = 0; nt < 4; ++nt)
                acc[mt][nt] = MFMA16(aF[mt], bF[nt], acc[mt][nt]);
        __syncthreads();
    };

    step(As0, Bs0, As1, Bs1,  32, true);
    step(As1, Bs1, As0, Bs0,  64, true);
    step(As0, Bs0, As1, Bs1,  96, true);
    step(As1, Bs1, As0, Bs0, 128, true);
    step(As0, Bs0, As1, Bs1, 160, true);
    step(As1, Bs1, As0, Bs0, 192, true);
    step(As0, Bs0, As1, Bs1, 224, true);
    step(As1, Bs1, As0, Bs0,   0, false);

    #pragma unroll
    for (int mt = 0; mt < 2; ++mt) {
        #pragma unroll
        for (int nt = 0; nt < 4; ++nt) {
            const int row = m0 + wr * 32 + mt * 16 + quad * 4;
            const int col = n0 + wc * 64 + nt * 16 + lc;
            const float bb = bo[col];
            #pragma unroll
            for (int rr = 0; rr < 4; ++rr)
                out[(size_t)(row + rr) * 256 + col] = acc[mt][nt][rr] + bb;
        }
    }
}

// ================= attention per (s,h): round-4 version (best: ~52us) ==========
// Swapped QK^T (S^T = mfma(K, Q)); in-register base-2 softmax; P -> PV B-operand
// via cvt_pk + permlane swaps; two 8-kt halves cap sc live range (VGPR 64).
// Round-6 lesson: do NOT hoist all 4 qf loads (VGPR 80, occupancy -14pt, +3us).
#define A_OFF_MASK 0
#define A_OFF_K    1024
#define A_OFF_VT   21504
#define A_LDS_TOT  (21504 + 32 * 264 * 2)   // 38400 B -> 4 blocks/CU

__global__ __launch_bounds__(256) void attn_kernel(
    const bf16* __restrict__ QG, const bf16* __restrict__ KV,
    const float* __restrict__ biasT, const float* __restrict__ bias_mask,
    const float* __restrict__ b_gL, bf16* __restrict__ OG)
{
    __shared__ __align__(16) char smem[A_LDS_TOT];
    float* maskadd = (float*)(smem + A_OFF_MASK);
    bf16*  Ks      = (bf16*)(smem + A_OFF_K);
    bf16*  Vt      = (bf16*)(smem + A_OFF_VT);

    const int tid  = threadIdx.x;
    const int wave = tid >> 6, lane = tid & 63;
    const int quad = lane >> 4, lc = lane & 15;
    const int h = blockIdx.x >> 7;       // all h of same s -> same XCD (bid%8 = s%8)
    const int s = blockIdx.x & 127;

    maskadd[tid] = (bias_mask[s * 256 + tid] - 1.0f) * (1e9f * L2E);
    {
        const bf16* kvrow = KV + (size_t)(s * 256 + tid) * 512 + h * 32;
        #pragma unroll
        for (int j = 0; j < 4; ++j)
            *(bf16x8*)(Ks + tid * 40 + j * 8) = *(const bf16x8*)(kvrow + j * 8);
        bf16x8 vx[4];
        #pragma unroll
        for (int j = 0; j < 4; ++j) vx[j] = *(const bf16x8*)(kvrow + 256 + j * 8);
        #pragma unroll
        for (int d = 0; d < 32; ++d)
            Vt[d * 264 + tid] = vx[d >> 3][d & 7];
    }
    __syncthreads();

    const f32x4 bg0 = *(const f32x4*)(b_gL + h * 32 + quad * 4);
    const f32x4 bg1 = *(const f32x4*)(b_gL + h * 32 + 16 + quad * 4);

    #pragma unroll 1
    for (int p = 0; p < 4; ++p) {
        const int q0 = (wave * 4 + p) * 16;

        bf16x8 qf = *(const bf16x8*)(QG + (size_t)(s * 256 + q0 + lc) * 512 + h * 32 + quad * 8);

        const float* bT = biasT + (((size_t)h * 256 + q0 + lc) << 8) + quad * 4;
        u32x2 cw[16];
        float sum = 0.f;
        #pragma unroll
        for (int half = 0; half < 2; ++half) {
            f32x4 sc[8];
            #pragma unroll
            for (int k8 = 0; k8 < 8; ++k8) {
                const int kt = half * 8 + k8;
                bf16x8 kf = *(const bf16x8*)(Ks + (kt * 16 + lc) * 40 + quad * 8);
                f32x4 z = {0.f, 0.f, 0.f, 0.f};
                sc[k8] = MFMA16(kf, qf, z);
            }
            #pragma unroll
            for (int k8 = 0; k8 < 8; ++k8) {
                const int kt = half * 8 + k8;
                f32x4 bv = *(const f32x4*)(bT + kt * 16);
                f32x4 mv = *(const f32x4*)(maskadd + kt * 16 + quad * 4);
                f32x4 t = sc[k8] + bv + mv;
                float e0 = fexp2(t[0]);
                float e1 = fexp2(t[1]);
                float e2 = fexp2(t[2]);
                float e3 = fexp2(t[3]);
                sum += (e0 + e1) + (e2 + e3);
                cw[kt] = u32x2{pk2(e0, e1), pk2(e2, e3)};
            }
            __builtin_amdgcn_sched_barrier(0x6);
        }

        const bf16* gp = QG + (size_t)(s * 256 + q0 + lc) * 512 + 256 + h * 32 + quad * 4;
        bf16x4 gv0 = *(const bf16x4*)(gp);
        bf16x4 gv1 = *(const bf16x4*)(gp + 16);

        f32x4 o0 = {0.f, 0.f, 0.f, 0.f}, o1 = {0.f, 0.f, 0.f, 0.f};
        #pragma unroll
        for (int ks = 0; ks < 8; ++ks) {
            u32 c0 = cw[2 * ks].x,     c1 = cw[2 * ks].y;
            u32 c2 = cw[2 * ks + 1].x, c3 = cw[2 * ks + 1].y;
            u32x2 s02 = __builtin_amdgcn_permlane32_swap(c0, c2, false, false);
            u32x2 s13 = __builtin_amdgcn_permlane32_swap(c1, c3, false, false);
            u32x2 e02 = __builtin_amdgcn_permlane16_swap(s02.x, s02.y, false, false);
            u32x2 e13 = __builtin_amdgcn_permlane16_swap(s13.x, s13.y, false, false);
            u32x4 pw = {e02.x, e13.x, e02.y, e13.y};
            bf16x8 pf = __builtin_bit_cast(bf16x8, pw);
            bf16x8 v0 = *(const bf16x8*)(Vt + lc * 264 + ks * 32 + quad * 8);
            bf16x8 v1 = *(const bf16x8*)(Vt + (16 + lc) * 264 + ks * 32 + quad * 8);
            o0 = MFMA16(v0, pf, o0);
            o1 = MFMA16(v1, pf, o1);
        }

        sum += __shfl_xor(sum, 16, 64);
        sum += __shfl_xor(sum, 32, 64);
        const float inv = frcp(sum);

        bf16* op = OG + (size_t)(s * 256 + q0 + lc) * 256 + h * 32 + quad * 4;
        #pragma unroll
        for (int nt = 0; nt < 2; ++nt) {
            f32x4 ov = nt ? o1 : o0;
            f32x4 bg = nt ? bg1 : bg0;
            bf16x4 gv = nt ? gv1 : gv0;
            bf16x4 ob;
            #pragma unroll
            for (int rr = 0; rr < 4; ++rr) {
                float e = fexp2(-((float)gv[rr] + bg[rr]));
                float g = frcp(1.0f + e);
                ob[rr] = (bf16)(ov[rr] * (inv * g));
            }
            *(bf16x4*)(op + nt * 16) = ob;
        }
    }
}

// ================= launch =================
extern "C" void kernel_launch(void* const* d_in, const int* in_sizes, int n_in,
                              void* d_out, int out_size, void* d_ws, size_t ws_size,
                              hipStream_t stream)
{
    (void)in_sizes; (void)n_in; (void)out_size; (void)ws_size;
    const float* q    = (const float*)d_in[0];
    const float* kv   = (const float*)d_in[1];
    const float* bias = (const float*)d_in[2];
    const float* mask = (const float*)d_in[3];
    const float* w_q  = (const float*)d_in[4];
    const float* w_k  = (const float*)d_in[5];
    const float* w_v  = (const float*)d_in[6];
    const float* w_g  = (const float*)d_in[7];
    const float* b_g  = (const float*)d_in[8];
    const float* w_o  = (const float*)d_in[9];
    const float* b_o  = (const float*)d_in[10];
    float* out = (float*)d_out;

    char* ws = (char*)d_ws;
    bf16*  OG    = (bf16*)(ws + 0);           // 16.78 MB
    bf16*  QG    = (bf16*)(ws + 33554432);    // 33.55 MB  [32768][512] = [Q*norm | G*l2e]
    bf16*  KV    = (bf16*)(ws + 67108864);    // 33.55 MB  [32768][512] = [K | V]
    float* biasT = (float*)(ws + 100663296);  //  2.10 MB  [h][q][k] * log2e
    bf16*  Wqg   = (bf16*)(ws + 102760448);   //  0.26 MB
    bf16*  Wkv   = (bf16*)(ws + 103022592);   //  0.26 MB
    bf16*  Wo    = (bf16*)(ws + 103284736);   //  0.13 MB
    float* b_gL  = (float*)(ws + 103415808);  //  1 KB

    prep_kernel<<<256, 256, 0, stream>>>(bias, w_q, w_k, w_v, w_g, w_o, b_g,
                                         biasT, Wqg, Wkv, Wo, b_gL);
    proj_kernel<<<2048, 256, 0, stream>>>(q, kv, Wqg, Wkv, QG, KV);
    attn_kernel<<<1024, 256, 0, stream>>>(QG, KV, biasT, mask, b_gL, OG);
    outproj_kernel<<<1024, 256, 0, stream>>>(OG, Wo, b_o, out);
}